// Round 1
// baseline (3694.798 us; speedup 1.0000x reference)
//
#include <hip/hip_runtime.h>

typedef float f32x4 __attribute__((ext_vector_type(4)));
typedef short s16x8 __attribute__((ext_vector_type(8)));
typedef unsigned short u16;

#define B_    256
#define HW_   196
#define E_    1024
#define H_    1024
#define L_    128
#define T_    48
#define FCOUT 1154   // L + H + 2
#define FCPAD 1216   // next multiple of 64

#define GJOBS 128            // gates tiles: (B/32) x (H/64) = 8 x 16
#define FJOBS 76             // fc tiles:    (B/64) x (FCPAD/64) = 4 x 19

__device__ __forceinline__ u16 f2bf(float x) {
  union { float f; unsigned u; } v; v.f = x;
  unsigned r = v.u + 0x7FFF + ((v.u >> 16) & 1);  // RNE
  return (u16)(r >> 16);
}
__device__ __forceinline__ float sigm(float x) { return 1.f / (1.f + expf(-x)); }

// async global->LDS, 16B per lane, wave-uniform LDS base + lane*16 (linear dest)
typedef __attribute__((address_space(1))) void GV;
typedef __attribute__((address_space(3))) void LV;
__device__ __forceinline__ void gl16(const u16* g, u16* l) {
  __builtin_amdgcn_global_load_lds((GV*)g, (LV*)l, 16, 0, 0);
}

// ---------------------------------------------------------------------------
// Setup: strided fp32 -> bf16 convert, 4 cols/thread (with zero row padding)
// ---------------------------------------------------------------------------
__global__ __launch_bounds__(256) void cvt_bf16_v4(
    const float* __restrict__ in, u16* __restrict__ out,
    int src_rows, int in_ld, int in_off, int cols4, long total4) {
  long idx = (long)blockIdx.x * 256 + threadIdx.x;
  if (idx >= total4) return;
  int r  = (int)(idx / cols4);
  int c4 = (int)(idx % cols4) * 4;
  f32x4 v = {0.f, 0.f, 0.f, 0.f};
  if (r < src_rows) v = *(const f32x4*)&in[(size_t)r * in_ld + in_off + c4];
  ushort4 o;
  ((u16*)&o)[0] = f2bf(v[0]); ((u16*)&o)[1] = f2bf(v[1]);
  ((u16*)&o)[2] = f2bf(v[2]); ((u16*)&o)[3] = f2bf(v[3]);
  *(ushort4*)&out[idx * 4] = o;
}

// ---------------------------------------------------------------------------
// img_mean[b][e] = mean over HW of image[b][hw][e]; store bf16 (4 e/thread)
// ---------------------------------------------------------------------------
__global__ __launch_bounds__(256) void img_mean_k(
    const float* __restrict__ image, u16* __restrict__ meanB) {
  int idx = blockIdx.x * 256 + threadIdx.x;   // b*(E/4) + e4
  int b  = idx >> 8;                          // E/4 = 256
  int e4 = (idx & 255) * 4;
  const float* p = image + (size_t)b * HW_ * E_ + e4;
  f32x4 s = {0.f, 0.f, 0.f, 0.f};
  #pragma unroll 4
  for (int hw = 0; hw < HW_; ++hw) s += *(const f32x4*)&p[(size_t)hw * E_];
  ushort4 o;
  #pragma unroll
  for (int c = 0; c < 4; ++c) ((u16*)&o)[c] = f2bf(s[c] * (1.0f / HW_));
  *(ushort4*)&meanB[(size_t)b * E_ + e4] = o;
}

// ---------------------------------------------------------------------------
// Setup NT GEMM (64x64 tile, 4 waves of 32x32 via 2x2 16x16x32 mfma).
// One-time kernels; kept in the simple reg-staged form.
// MODE 0: outF = acc + bias1[n] + bias2[n]     (gates_base)
// MODE 1: outB = bf16(tanh(acc + bias1[n]))    (h0)
// MODE 2: outF = tanh(acc + bias1[n])          (m0)
// ---------------------------------------------------------------------------
template <int MODE>
__global__ __launch_bounds__(256) void gemm_nt(
    const u16* __restrict__ A, int lda, const u16* __restrict__ Bp, int ldb, int K,
    const float* __restrict__ bias1, const float* __restrict__ bias2,
    float* __restrict__ outF, u16* __restrict__ outB, int ldc) {
  __shared__ __align__(16) u16 As[64][72];
  __shared__ __align__(16) u16 Bs[64][72];

  const int m0 = blockIdx.x * 64;
  const int n0 = blockIdx.y * 64;
  const int tid  = threadIdx.x;
  const int lane = tid & 63;
  const int wave = tid >> 6;
  const int wm = wave & 1, wn = wave >> 1;
  const int quad = lane >> 4, l16 = lane & 15;
  const int loadRow = tid >> 3;
  const int loadCol = (tid & 7) * 8;

  f32x4 acc[2][2] = {};

  for (int kb = 0; kb < K; kb += 64) {
    __syncthreads();
    #pragma unroll
    for (int p = 0; p < 2; ++p) {
      int r = loadRow + p * 32;
      *(uint4*)&As[r][loadCol] = *(const uint4*)&A [(size_t)(m0 + r) * lda + kb + loadCol];
      *(uint4*)&Bs[r][loadCol] = *(const uint4*)&Bp[(size_t)(n0 + r) * ldb + kb + loadCol];
    }
    __syncthreads();
    #pragma unroll
    for (int ks = 0; ks < 64; ks += 32) {
      s16x8 a0v = *(const s16x8*)&As[wm * 32      + l16][ks + quad * 8];
      s16x8 a1v = *(const s16x8*)&As[wm * 32 + 16 + l16][ks + quad * 8];
      s16x8 b0v = *(const s16x8*)&Bs[wn * 32      + l16][ks + quad * 8];
      s16x8 b1v = *(const s16x8*)&Bs[wn * 32 + 16 + l16][ks + quad * 8];
      acc[0][0] = __builtin_amdgcn_mfma_f32_16x16x32_bf16(a0v, b0v, acc[0][0], 0, 0, 0);
      acc[0][1] = __builtin_amdgcn_mfma_f32_16x16x32_bf16(a0v, b1v, acc[0][1], 0, 0, 0);
      acc[1][0] = __builtin_amdgcn_mfma_f32_16x16x32_bf16(a1v, b0v, acc[1][0], 0, 0, 0);
      acc[1][1] = __builtin_amdgcn_mfma_f32_16x16x32_bf16(a1v, b1v, acc[1][1], 0, 0, 0);
    }
  }

  #pragma unroll
  for (int mi = 0; mi < 2; ++mi) {
    #pragma unroll
    for (int ni = 0; ni < 2; ++ni) {
      #pragma unroll
      for (int r = 0; r < 4; ++r) {
        int m = m0 + wm * 32 + mi * 16 + quad * 4 + r;
        int n = n0 + wn * 32 + ni * 16 + l16;
        float v = acc[mi][ni][r];
        if constexpr (MODE == 0) {
          outF[(size_t)m * ldc + n] = v + bias1[n] + bias2[n];
        } else if constexpr (MODE == 1) {
          outB[(size_t)m * ldc + n] = f2bf(tanhf(v + bias1[n]));
        } else {
          outF[(size_t)m * ldc + n] = tanhf(v + bias1[n]);
        }
      }
    }
  }
}

// ---------------------------------------------------------------------------
// One scan phase per launch; kernel boundary = barrier + coherence (no
// reliance on grid.sync cross-XCD visibility — R2 failed there).
//
// NEW (this round): double-buffered, global_load_lds-staged K-loops.
//  * LDS tiles are LINEAR (row stride 128 B); the bank conflict that a
//    linear layout would cause on ds_read_b128 is fixed by the both-sides
//    XOR swizzle: source global address pre-swizzled with
//    col_byte ^ ((row&7)<<4), and the same XOR applied on the read side.
//  * Per K-step: issue next tile's global_load_lds into the other buffer,
//    compute current tile, then ONE __syncthreads() (its vmcnt(0) drain is
//    exactly the depth-1 pipeline wait). Stage latency hides under MFMA.
// ---------------------------------------------------------------------------
struct GStage {                       // gates: A 32x64, B 256x64, both x2
  u16 A0[32 * 64], A1[32 * 64];
  u16 B0[256 * 64], B1[256 * 64];
};                                    // 73728 B
struct FStage {                       // fc: A 64x64, B 64x64, both x2
  u16 A0[64 * 64], A1[64 * 64];
  u16 B0[64 * 64], B1[64 * 64];
};                                    // 32768 B
union __align__(16) SharedU {
  GStage g;
  FStage f;
  float gs[4][32][68];                // gate exchange, padded to 68 (34816 B)
};

__global__ __launch_bounds__(256) void step_k(
    const u16* __restrict__ labB,    // B x T x L
    const u16* __restrict__ WihL,    // 4H x L
    const u16* __restrict__ WhhB,    // 4H x H
    const u16* __restrict__ WfcB,    // FCPAD x H
    const float* __restrict__ gbase, // B x 4H (includes b_ih + b_hh)
    const float* __restrict__ b_fc,  // FCOUT
    const u16* __restrict__ hcur, u16* __restrict__ hnext,
    float* __restrict__ mS,          // B x H f32
    const int* __restrict__ length,
    float* __restrict__ out,
    int p) {
  __shared__ SharedU sh;

  const int bid  = blockIdx.x;
  const int tid  = threadIdx.x;
  const int lane = tid & 63;
  const int wave = tid >> 6;
  const int quad = lane >> 4, l16 = lane & 15;
  const int lr = lane >> 3, lc = lane & 7;
  const int cswz = 8 * (lc ^ lr);     // source col pre-swizzle (u16 units)
  const int x16  = (l16 & 7) << 4;    // read-side XOR (bytes)

  if (p < T_ && bid < GJOBS) {
    // ---------------- gates(p) + LSTM update ----------------
    const int mb = bid >> 4;        // 0..7   (b tile of 32)
    const int jb = bid & 15;        // 0..15  (j tile of 64)

    // per-lane source element offsets (constant over kb; +64 per K-step)
    const long offA0 = (long)(mb * 32 + wave * 8 + lr) * (T_ * L_) + (long)p * L_ + cswz;
    const long offA1 = (long)(mb * 32 + wave * 8 + lr) * H_ + cswz;
    const long wrow  = (long)(wave * 1024 + jb * 64 + lr);   // + q*8 rows later
    const long offB0 = wrow * L_ + cswz;
    const long offB1 = wrow * H_ + cswz;

    auto stage = [&](int kb, int bb) {
      u16* aD = (bb ? sh.g.A1 : sh.g.A0) + wave * 512;    // 1024 B / wave
      u16* bD = (bb ? sh.g.B1 : sh.g.B0) + wave * 4096;   // 8192 B / wave
      if (kb < 2) {                                       // label @ W_ihL^T
        const long k0 = (long)kb * 64;
        gl16(labB + offA0 + k0, aD);
        #pragma unroll
        for (int q = 0; q < 8; ++q)
          gl16(WihL + offB0 + (long)q * (8 * L_) + k0, bD + q * 512);
      } else {                                            // h @ W_hh^T
        const long k0 = (long)(kb - 2) * 64;
        gl16(hcur + offA1 + k0, aD);
        #pragma unroll
        for (int q = 0; q < 8; ++q)
          gl16(WhhB + offB1 + (long)q * (8 * H_) + k0, bD + q * 512);
      }
    };

    f32x4 acc[2][4] = {};
    stage(0, 0);
    __syncthreads();                 // vmcnt(0) drain + barrier: tile 0 ready

    for (int kb = 0; kb < 18; ++kb) {
      const int bb = kb & 1;
      if (kb + 1 < 18) stage(kb + 1, bb ^ 1);   // prefetch next tile (async)
      const char* At = (const char*)(bb ? sh.g.A1 : sh.g.A0);
      const char* Bt = (const char*)(bb ? sh.g.B1 : sh.g.B0);
      #pragma unroll
      for (int ksi = 0; ksi < 2; ++ksi) {
        const int cs = (ksi * 64 + quad * 16) ^ x16;
        s16x8 av[2], bv[4];
        av[0] = *(const s16x8*)(At + l16 * 128 + cs);
        av[1] = *(const s16x8*)(At + (16 + l16) * 128 + cs);
        #pragma unroll
        for (int ni = 0; ni < 4; ++ni)
          bv[ni] = *(const s16x8*)(Bt + (wave * 64 + ni * 16 + l16) * 128 + cs);
        #pragma unroll
        for (int mi = 0; mi < 2; ++mi)
          #pragma unroll
          for (int ni = 0; ni < 4; ++ni)
            acc[mi][ni] = __builtin_amdgcn_mfma_f32_16x16x32_bf16(
                av[mi], bv[ni], acc[mi][ni], 0, 0, 0);
      }
      __syncthreads();               // drains prefetch; next tile ready
    }

    // exchange gates through LDS (aliases staging bufs: safe after barrier)
    #pragma unroll
    for (int mi = 0; mi < 2; ++mi)
      #pragma unroll
      for (int ni = 0; ni < 4; ++ni)
        #pragma unroll
        for (int r = 0; r < 4; ++r)
          sh.gs[wave][mi * 16 + quad * 4 + r][ni * 16 + l16] = acc[mi][ni][r];
    __syncthreads();

    // vectorized LSTM update: 2 tasks/thread, float4 per task
    #pragma unroll
    for (int q = 0; q < 2; ++q) {
      const int tau = tid + q * 256;
      const int bl = tau >> 4, j4 = (tau & 15) * 4;
      const int b = mb * 32 + bl, j = jb * 64 + j4;
      const float* gb = gbase + (size_t)b * (4 * H_) + j;
      f32x4 gi = *(const f32x4*)&sh.gs[0][bl][j4];
      f32x4 gf = *(const f32x4*)&sh.gs[1][bl][j4];
      f32x4 gg = *(const f32x4*)&sh.gs[2][bl][j4];
      f32x4 go = *(const f32x4*)&sh.gs[3][bl][j4];
      f32x4 bi  = *(const f32x4*)(gb);
      f32x4 bff = *(const f32x4*)(gb + H_);
      f32x4 bg  = *(const f32x4*)(gb + 2 * H_);
      f32x4 bo  = *(const f32x4*)(gb + 3 * H_);
      float* mp = mS + (size_t)b * H_ + j;
      f32x4 m = *(f32x4*)mp;
      ushort4 hb;
      #pragma unroll
      for (int c = 0; c < 4; ++c) {
        float I = sigm(gi[c] + bi[c]);
        float F = sigm(gf[c] + bff[c]);
        float G = tanhf(gg[c] + bg[c]);
        float O = sigm(go[c] + bo[c]);
        float mm = F * m[c] + I * G;
        m[c] = mm;
        ((u16*)&hb)[c] = f2bf(O * tanhf(mm));
      }
      *(f32x4*)mp = m;
      *(ushort4*)&hnext[(size_t)b * H_ + j] = hb;
    }
  } else if (p >= 1 && bid >= GJOBS && bid < GJOBS + FJOBS) {
    // ---------------- fc(p-1) ----------------
    const int t   = p - 1;
    const int fid = bid - GJOBS;
    const int m0 = (fid / 19) * 64;
    const int n0 = (fid % 19) * 64;
    const int wm = wave & 1, wn = wave >> 1;

    const long offA = (long)(m0 + wave * 16 + lr) * H_ + cswz;  // + i*8 rows
    const long offB = (long)(n0 + wave * 16 + lr) * H_ + cswz;

    auto stageF = [&](int kb, int bb) {
      u16* aD = (bb ? sh.f.A1 : sh.f.A0) + wave * 1024;   // 2048 B / wave
      u16* bD = (bb ? sh.f.B1 : sh.f.B0) + wave * 1024;
      const long k0 = (long)kb * 64;
      #pragma unroll
      for (int i = 0; i < 2; ++i) {
        gl16(hcur + offA + (long)i * (8 * H_) + k0, aD + i * 512);
        gl16(WfcB + offB + (long)i * (8 * H_) + k0, bD + i * 512);
      }
    };

    f32x4 acc[2][2] = {};
    stageF(0, 0);
    __syncthreads();

    for (int kb = 0; kb < 16; ++kb) {
      const int bb = kb & 1;
      if (kb + 1 < 16) stageF(kb + 1, bb ^ 1);
      const char* At = (const char*)(bb ? sh.f.A1 : sh.f.A0);
      const char* Bt = (const char*)(bb ? sh.f.B1 : sh.f.B0);
      #pragma unroll
      for (int ksi = 0; ksi < 2; ++ksi) {
        const int cs = (ksi * 64 + quad * 16) ^ x16;
        s16x8 a0v = *(const s16x8*)(At + (wm * 32      + l16) * 128 + cs);
        s16x8 a1v = *(const s16x8*)(At + (wm * 32 + 16 + l16) * 128 + cs);
        s16x8 b0v = *(const s16x8*)(Bt + (wn * 32      + l16) * 128 + cs);
        s16x8 b1v = *(const s16x8*)(Bt + (wn * 32 + 16 + l16) * 128 + cs);
        acc[0][0] = __builtin_amdgcn_mfma_f32_16x16x32_bf16(a0v, b0v, acc[0][0], 0, 0, 0);
        acc[0][1] = __builtin_amdgcn_mfma_f32_16x16x32_bf16(a0v, b1v, acc[0][1], 0, 0, 0);
        acc[1][0] = __builtin_amdgcn_mfma_f32_16x16x32_bf16(a1v, b0v, acc[1][0], 0, 0, 0);
        acc[1][1] = __builtin_amdgcn_mfma_f32_16x16x32_bf16(a1v, b1v, acc[1][1], 0, 0, 0);
      }
      __syncthreads();
    }

    #pragma unroll
    for (int mi = 0; mi < 2; ++mi) {
      #pragma unroll
      for (int ni = 0; ni < 2; ++ni) {
        #pragma unroll
        for (int r = 0; r < 4; ++r) {
          int m = m0 + wm * 32 + mi * 16 + quad * 4 + r;
          int n = n0 + wn * 32 + ni * 16 + l16;
          if (n < FCOUT) {
            float rv = fmaxf(acc[mi][ni][r] + b_fc[n], 0.f);
            float msk = (t < length[m]) ? 1.f : 0.f;
            if (n < L_) {
              out[(size_t)m * (T_ * L_) + t * L_ + n] = rv * msk;
            } else if (n < L_ + H_) {
              out[(size_t)(B_ * T_ * L_) + (size_t)m * (T_ * H_) + t * H_ + (n - L_)] = rv * msk;
            } else if (n == L_ + H_) {
              out[(size_t)B_ * T_ * (L_ + H_) + m * T_ + t] = expf(rv) * msk;
            } else {
              out[(size_t)B_ * T_ * (L_ + H_ + 1) + m * T_ + t] = sigm(rv) * msk;
            }
          }
        }
      }
    }
  }
}

// ---------------------------------------------------------------------------
extern "C" void kernel_launch(void* const* d_in, const int* in_sizes, int n_in,
                              void* d_out, int out_size, void* d_ws, size_t ws_size,
                              hipStream_t stream) {
  const float* image  = (const float*)d_in[0];
  const float* label  = (const float*)d_in[1];
  const int*   length = (const int*)  d_in[2];
  const float* W_h    = (const float*)d_in[3];
  const float* b_h    = (const float*)d_in[4];
  const float* W_m    = (const float*)d_in[5];
  const float* b_m    = (const float*)d_in[6];
  const float* W_ih   = (const float*)d_in[7];
  const float* W_hh   = (const float*)d_in[8];
  const float* b_ih   = (const float*)d_in[9];
  const float* b_hh   = (const float*)d_in[10];
  const float* W_fc   = (const float*)d_in[11];
  const float* b_fc   = (const float*)d_in[12];
  float* out = (float*)d_out;

  char* ws = (char*)d_ws;
  size_t off = 0;
  auto alloc = [&](size_t bytes) -> void* {
    void* p = ws + off;
    off = (off + bytes + 255) & ~(size_t)255;
    return p;
  };
  u16*   meanB = (u16*)  alloc((size_t)B_ * E_ * 2);
  u16*   WhB   = (u16*)  alloc((size_t)H_ * E_ * 2);
  u16*   WmB   = (u16*)  alloc((size_t)H_ * E_ * 2);
  u16*   WihE  = (u16*)  alloc((size_t)4 * H_ * E_ * 2);
  u16*   WihL  = (u16*)  alloc((size_t)4 * H_ * L_ * 2);
  u16*   WhhB  = (u16*)  alloc((size_t)4 * H_ * H_ * 2);
  u16*   WfcB  = (u16*)  alloc((size_t)FCPAD * H_ * 2);
  u16*   labB  = (u16*)  alloc((size_t)B_ * T_ * L_ * 2);
  float* gbase = (float*)alloc((size_t)B_ * 4 * H_ * 4);
  u16*   hbuf0 = (u16*)  alloc((size_t)B_ * H_ * 2);
  u16*   hbuf1 = (u16*)  alloc((size_t)B_ * H_ * 2);
  float* mS    = (float*)alloc((size_t)B_ * H_ * 4);

  auto cvt = [&](const float* in, u16* o, int rows, int src_rows, int in_ld,
                 int in_off, int cols) {
    long total4 = (long)rows * cols / 4;
    int blocks = (int)((total4 + 255) / 256);
    cvt_bf16_v4<<<blocks, 256, 0, stream>>>(in, o, src_rows, in_ld, in_off,
                                            cols / 4, total4);
  };

  // --- setup: weight/label conversion to bf16 ---
  cvt(W_h,  WhB,  H_,     H_,     E_,      0,  E_);
  cvt(W_m,  WmB,  H_,     H_,     E_,      0,  E_);
  cvt(W_ih, WihE, 4 * H_, 4 * H_, E_ + L_, 0,  E_);   // columns [0, E)
  cvt(W_ih, WihL, 4 * H_, 4 * H_, E_ + L_, E_, L_);   // columns [E, E+L)
  cvt(W_hh, WhhB, 4 * H_, 4 * H_, H_,      0,  H_);
  cvt(W_fc, WfcB, FCPAD,  FCOUT,  H_,      0,  H_);   // zero-padded rows
  cvt(label, labB, B_, B_, T_ * L_, 0, T_ * L_);

  img_mean_k<<<(B_ * E_ / 4) / 256, 256, 0, stream>>>(image, meanB);

  // --- setup GEMMs ---
  // h0 = tanh(mean @ W_h^T + b_h) -> bf16 (h_state[-1] in hbuf0)
  gemm_nt<1><<<dim3(B_ / 64, H_ / 64), 256, 0, stream>>>(
      meanB, E_, WhB, E_, E_, b_h, nullptr, nullptr, hbuf0, H_);
  // m0 = tanh(mean @ W_m^T + b_m) -> f32
  gemm_nt<2><<<dim3(B_ / 64, H_ / 64), 256, 0, stream>>>(
      meanB, E_, WmB, E_, E_, b_m, nullptr, mS, nullptr, H_);
  // gates_base = mean @ W_ihE^T + b_ih + b_hh -> f32
  gemm_nt<0><<<dim3(B_ / 64, (4 * H_) / 64), 256, 0, stream>>>(
      meanB, E_, WihE, E_, E_, b_ih, b_hh, gbase, nullptr, 4 * H_);

  // --- the scan: one launch per phase; kernel boundary = sync ---
  for (int p = 0; p <= T_; ++p) {
    u16* hcur  = (p & 1) ? hbuf1 : hbuf0;
    u16* hnext = (p & 1) ? hbuf0 : hbuf1;
    step_k<<<GJOBS + FJOBS, 256, 0, stream>>>(
        labB, WihL, WhhB, WfcB, gbase, b_fc, hcur, hnext, mS, length, out, p);
  }
}

// Round 2
// 1298.268 us; speedup vs baseline: 2.8459x; 2.8459x over previous
//
#include <hip/hip_runtime.h>

typedef float f32x4 __attribute__((ext_vector_type(4)));
typedef short s16x8 __attribute__((ext_vector_type(8)));
typedef unsigned short u16;

#define B_    256
#define HW_   196
#define E_    1024
#define H_    1024
#define L_    128
#define T_    48
#define FCOUT 1154   // L + H + 2
#define FCPAD 1216   // next multiple of 64

#define GJOBS 128            // gates tiles: (B/32) x (H/64) = 8 x 16
#define FJOBS 76             // fc tiles:    (B/64) x (FCPAD/64) = 4 x 19

__device__ __forceinline__ u16 f2bf(float x) {
  union { float f; unsigned u; } v; v.f = x;
  unsigned r = v.u + 0x7FFF + ((v.u >> 16) & 1);  // RNE
  return (u16)(r >> 16);
}
__device__ __forceinline__ float sigm(float x) { return 1.f / (1.f + expf(-x)); }

// ---------------------------------------------------------------------------
// Setup: strided fp32 -> bf16 convert, 4 cols/thread (with zero row padding)
// ---------------------------------------------------------------------------
__global__ __launch_bounds__(256) void cvt_bf16_v4(
    const float* __restrict__ in, u16* __restrict__ out,
    int src_rows, int in_ld, int in_off, int cols4, long total4) {
  long idx = (long)blockIdx.x * 256 + threadIdx.x;
  if (idx >= total4) return;
  int r  = (int)(idx / cols4);
  int c4 = (int)(idx % cols4) * 4;
  f32x4 v = {0.f, 0.f, 0.f, 0.f};
  if (r < src_rows) v = *(const f32x4*)&in[(size_t)r * in_ld + in_off + c4];
  ushort4 o;
  ((u16*)&o)[0] = f2bf(v[0]); ((u16*)&o)[1] = f2bf(v[1]);
  ((u16*)&o)[2] = f2bf(v[2]); ((u16*)&o)[3] = f2bf(v[3]);
  *(ushort4*)&out[idx * 4] = o;
}

// ---------------------------------------------------------------------------
// img_mean[b][e] = mean over HW of image[b][hw][e]; store bf16 (4 e/thread)
// ---------------------------------------------------------------------------
__global__ __launch_bounds__(256) void img_mean_k(
    const float* __restrict__ image, u16* __restrict__ meanB) {
  int idx = blockIdx.x * 256 + threadIdx.x;   // b*(E/4) + e4
  int b  = idx >> 8;                          // E/4 = 256
  int e4 = (idx & 255) * 4;
  const float* p = image + (size_t)b * HW_ * E_ + e4;
  f32x4 s = {0.f, 0.f, 0.f, 0.f};
  #pragma unroll 4
  for (int hw = 0; hw < HW_; ++hw) s += *(const f32x4*)&p[(size_t)hw * E_];
  ushort4 o;
  #pragma unroll
  for (int c = 0; c < 4; ++c) ((u16*)&o)[c] = f2bf(s[c] * (1.0f / HW_));
  *(ushort4*)&meanB[(size_t)b * E_ + e4] = o;
}

// ---------------------------------------------------------------------------
// Setup NT GEMM (64x64 tile, 4 waves of 32x32 via 2x2 16x16x32 mfma).
// One-time kernels; simple reg-staged form.
// MODE 0: outF = acc + bias1[n] + bias2[n]     (gates_base)
// MODE 1: outB = bf16(tanh(acc + bias1[n]))    (h0)
// MODE 2: outF = tanh(acc + bias1[n])          (m0)
// ---------------------------------------------------------------------------
template <int MODE>
__global__ __launch_bounds__(256) void gemm_nt(
    const u16* __restrict__ A, int lda, const u16* __restrict__ Bp, int ldb, int K,
    const float* __restrict__ bias1, const float* __restrict__ bias2,
    float* __restrict__ outF, u16* __restrict__ outB, int ldc) {
  __shared__ __align__(16) u16 As[64][72];
  __shared__ __align__(16) u16 Bs[64][72];

  const int m0 = blockIdx.x * 64;
  const int n0 = blockIdx.y * 64;
  const int tid  = threadIdx.x;
  const int lane = tid & 63;
  const int wave = tid >> 6;
  const int wm = wave & 1, wn = wave >> 1;
  const int quad = lane >> 4, l16 = lane & 15;
  const int loadRow = tid >> 3;
  const int loadCol = (tid & 7) * 8;

  f32x4 acc[2][2] = {};

  for (int kb = 0; kb < K; kb += 64) {
    __syncthreads();
    #pragma unroll
    for (int p = 0; p < 2; ++p) {
      int r = loadRow + p * 32;
      *(uint4*)&As[r][loadCol] = *(const uint4*)&A [(size_t)(m0 + r) * lda + kb + loadCol];
      *(uint4*)&Bs[r][loadCol] = *(const uint4*)&Bp[(size_t)(n0 + r) * ldb + kb + loadCol];
    }
    __syncthreads();
    #pragma unroll
    for (int ks = 0; ks < 64; ks += 32) {
      s16x8 a0v = *(const s16x8*)&As[wm * 32      + l16][ks + quad * 8];
      s16x8 a1v = *(const s16x8*)&As[wm * 32 + 16 + l16][ks + quad * 8];
      s16x8 b0v = *(const s16x8*)&Bs[wn * 32      + l16][ks + quad * 8];
      s16x8 b1v = *(const s16x8*)&Bs[wn * 32 + 16 + l16][ks + quad * 8];
      acc[0][0] = __builtin_amdgcn_mfma_f32_16x16x32_bf16(a0v, b0v, acc[0][0], 0, 0, 0);
      acc[0][1] = __builtin_amdgcn_mfma_f32_16x16x32_bf16(a0v, b1v, acc[0][1], 0, 0, 0);
      acc[1][0] = __builtin_amdgcn_mfma_f32_16x16x32_bf16(a1v, b0v, acc[1][0], 0, 0, 0);
      acc[1][1] = __builtin_amdgcn_mfma_f32_16x16x32_bf16(a1v, b1v, acc[1][1], 0, 0, 0);
    }
  }

  #pragma unroll
  for (int mi = 0; mi < 2; ++mi) {
    #pragma unroll
    for (int ni = 0; ni < 2; ++ni) {
      #pragma unroll
      for (int r = 0; r < 4; ++r) {
        int m = m0 + wm * 32 + mi * 16 + quad * 4 + r;
        int n = n0 + wn * 32 + ni * 16 + l16;
        float v = acc[mi][ni][r];
        if constexpr (MODE == 0) {
          outF[(size_t)m * ldc + n] = v + bias1[n] + bias2[n];
        } else if constexpr (MODE == 1) {
          outB[(size_t)m * ldc + n] = f2bf(tanhf(v + bias1[n]));
        } else {
          outF[(size_t)m * ldc + n] = tanhf(v + bias1[n]);
        }
      }
    }
  }
}

// ---------------------------------------------------------------------------
// One scan phase per launch; kernel boundary = barrier + coherence.
//
// R2: 512-thread blocks, two 4-wave groups per block, intra-block SPLIT-K.
//  * gates: group 0 does K [0,576) (2 label steps + 7 Whh steps),
//           group 1 does K [576,1152) (9 Whh steps)  -> 9 K-steps, was 18.
//  * fc:    group g does K [g*512, g*512+512)        -> 8 K-steps, was 16.
//  * memory pattern identical to the verified r0 kernel (reg-staged uint4
//    into [72]-padded LDS, same fragment reads, same MFMA order).
//  * partial sums combined through the existing LDS exchange.
//  * 8 waves/block = 2 waves/SIMD: the two groups' staging loads overlap
//    in the memory system; the serial latency chain is halved.
// ---------------------------------------------------------------------------
struct GS8 { u16 A[2][32][72]; u16 B[2][256][72]; };   // 82944 B
struct FS8 { u16 A[2][64][72]; u16 B[2][64][72]; };    // 36864 B
union __align__(16) SharedU {
  GS8 g;
  FS8 f;
  float gs[2][4][32][68];                              // 69632 B
  float fs[64][68];                                    // 17408 B
};

__global__ __launch_bounds__(512) void step_k(
    const u16* __restrict__ labB,    // B x T x L
    const u16* __restrict__ WihL,    // 4H x L
    const u16* __restrict__ WhhB,    // 4H x H
    const u16* __restrict__ WfcB,    // FCPAD x H
    const float* __restrict__ gbase, // B x 4H (includes b_ih + b_hh)
    const float* __restrict__ b_fc,  // FCOUT
    const u16* __restrict__ hcur, u16* __restrict__ hnext,
    float* __restrict__ mS,          // B x H f32
    const int* __restrict__ length,
    float* __restrict__ out,
    int p) {
  __shared__ SharedU sh;

  const int bid  = blockIdx.x;
  const int tid  = threadIdx.x;
  const int g2   = tid >> 8;          // K-half group 0/1
  const int gtid = tid & 255;         // index within group
  const int lane = tid & 63;
  const int wave = tid >> 6;          // 0..7
  const int sw   = wave & 3;          // wave role within group
  const int quad = lane >> 4, l16 = lane & 15;
  const int ar = gtid >> 3;           // load row 0..31
  const int ac = (gtid & 7) * 8;      // load col chunk

  if (p < T_ && bid < GJOBS) {
    // ---------------- gates(p) + LSTM update ----------------
    const int mb = bid >> 4;        // 0..7   (b tile of 32)
    const int jb = bid & 15;        // 0..15  (j tile of 64)
    f32x4 acc[2][4] = {};

    for (int kb = 0; kb < 9; ++kb) {
      const int seg1 = (g2 == 1) || (kb >= 2);   // Whh/hcur segment?
      const int k0 = g2 ? (448 + kb * 64) : (seg1 ? (kb - 2) * 64 : kb * 64);

      __syncthreads();
      {
        const u16* Ap = seg1
            ? hcur + (size_t)(mb * 32 + ar) * H_ + k0 + ac
            : labB + (size_t)(mb * 32 + ar) * (T_ * L_) + (size_t)p * L_ + k0 + ac;
        *(uint4*)&sh.g.A[g2][ar][ac] = *(const uint4*)Ap;
        const u16* Bw  = seg1 ? WhhB : WihL;
        const int  ldb = seg1 ? H_ : L_;
        #pragma unroll
        for (int q = 0; q < 8; ++q) {
          int rr = ar + q * 32;                       // 0..255
          int grow = (rr >> 6) * H_ + jb * 64 + (rr & 63);
          *(uint4*)&sh.g.B[g2][rr][ac] =
              *(const uint4*)&Bw[(size_t)grow * ldb + k0 + ac];
        }
      }
      __syncthreads();
      #pragma unroll
      for (int ks = 0; ks < 64; ks += 32) {
        s16x8 av[2], bv[4];
        av[0] = *(const s16x8*)&sh.g.A[g2][l16][ks + quad * 8];
        av[1] = *(const s16x8*)&sh.g.A[g2][16 + l16][ks + quad * 8];
        #pragma unroll
        for (int ni = 0; ni < 4; ++ni)
          bv[ni] = *(const s16x8*)&sh.g.B[g2][sw * 64 + ni * 16 + l16][ks + quad * 8];
        #pragma unroll
        for (int mi = 0; mi < 2; ++mi)
          #pragma unroll
          for (int ni = 0; ni < 4; ++ni)
            acc[mi][ni] = __builtin_amdgcn_mfma_f32_16x16x32_bf16(
                av[mi], bv[ni], acc[mi][ni], 0, 0, 0);
      }
    }

    // exchange both groups' partial gates through LDS (aliases staging bufs)
    __syncthreads();
    #pragma unroll
    for (int mi = 0; mi < 2; ++mi)
      #pragma unroll
      for (int ni = 0; ni < 4; ++ni)
        #pragma unroll
        for (int r = 0; r < 4; ++r)
          sh.gs[g2][sw][mi * 16 + quad * 4 + r][ni * 16 + l16] = acc[mi][ni][r];
    __syncthreads();

    // elementwise LSTM update: 512 threads x 4 elems (f32x4)
    {
      const int bl = tid >> 4, j4 = (tid & 15) * 4;
      const int b = mb * 32 + bl, j = jb * 64 + j4;
      const float* gb = gbase + (size_t)b * (4 * H_) + j;
      f32x4 gi = *(const f32x4*)&sh.gs[0][0][bl][j4] + *(const f32x4*)&sh.gs[1][0][bl][j4];
      f32x4 gf = *(const f32x4*)&sh.gs[0][1][bl][j4] + *(const f32x4*)&sh.gs[1][1][bl][j4];
      f32x4 gg = *(const f32x4*)&sh.gs[0][2][bl][j4] + *(const f32x4*)&sh.gs[1][2][bl][j4];
      f32x4 go = *(const f32x4*)&sh.gs[0][3][bl][j4] + *(const f32x4*)&sh.gs[1][3][bl][j4];
      f32x4 bi  = *(const f32x4*)(gb);
      f32x4 bff = *(const f32x4*)(gb + H_);
      f32x4 bg  = *(const f32x4*)(gb + 2 * H_);
      f32x4 bo  = *(const f32x4*)(gb + 3 * H_);
      float* mp = mS + (size_t)b * H_ + j;
      f32x4 m = *(f32x4*)mp;
      ushort4 hb;
      #pragma unroll
      for (int c = 0; c < 4; ++c) {
        float I = sigm(gi[c] + bi[c]);
        float F = sigm(gf[c] + bff[c]);
        float G = tanhf(gg[c] + bg[c]);
        float O = sigm(go[c] + bo[c]);
        float mm = F * m[c] + I * G;
        m[c] = mm;
        ((u16*)&hb)[c] = f2bf(O * tanhf(mm));
      }
      *(f32x4*)mp = m;
      *(ushort4*)&hnext[(size_t)b * H_ + j] = hb;
    }
  } else if (p >= 1 && bid >= GJOBS && bid < GJOBS + FJOBS) {
    // ---------------- fc(p-1) ----------------
    const int t   = p - 1;
    const int fid = bid - GJOBS;
    const int m0 = (fid / 19) * 64;
    const int n0 = (fid % 19) * 64;
    const int wm = sw & 1, wn = sw >> 1;
    f32x4 acc[2][2] = {};

    for (int kb = 0; kb < 8; ++kb) {
      const int k0 = g2 * 512 + kb * 64;
      __syncthreads();
      #pragma unroll
      for (int pp = 0; pp < 2; ++pp) {
        int r = ar + pp * 32;
        *(uint4*)&sh.f.A[g2][r][ac] = *(const uint4*)&hcur[(size_t)(m0 + r) * H_ + k0 + ac];
        *(uint4*)&sh.f.B[g2][r][ac] = *(const uint4*)&WfcB[(size_t)(n0 + r) * H_ + k0 + ac];
      }
      __syncthreads();
      #pragma unroll
      for (int ks = 0; ks < 64; ks += 32) {
        s16x8 a0v = *(const s16x8*)&sh.f.A[g2][wm * 32      + l16][ks + quad * 8];
        s16x8 a1v = *(const s16x8*)&sh.f.A[g2][wm * 32 + 16 + l16][ks + quad * 8];
        s16x8 b0v = *(const s16x8*)&sh.f.B[g2][wn * 32      + l16][ks + quad * 8];
        s16x8 b1v = *(const s16x8*)&sh.f.B[g2][wn * 32 + 16 + l16][ks + quad * 8];
        acc[0][0] = __builtin_amdgcn_mfma_f32_16x16x32_bf16(a0v, b0v, acc[0][0], 0, 0, 0);
        acc[0][1] = __builtin_amdgcn_mfma_f32_16x16x32_bf16(a0v, b1v, acc[0][1], 0, 0, 0);
        acc[1][0] = __builtin_amdgcn_mfma_f32_16x16x32_bf16(a1v, b0v, acc[1][0], 0, 0, 0);
        acc[1][1] = __builtin_amdgcn_mfma_f32_16x16x32_bf16(a1v, b1v, acc[1][1], 0, 0, 0);
      }
    }

    // combine K-halves: group 1 -> LDS, group 0 adds
    __syncthreads();
    if (g2 == 1) {
      #pragma unroll
      for (int mi = 0; mi < 2; ++mi)
        #pragma unroll
        for (int ni = 0; ni < 2; ++ni)
          #pragma unroll
          for (int r = 0; r < 4; ++r)
            sh.fs[wm * 32 + mi * 16 + quad * 4 + r][wn * 32 + ni * 16 + l16] =
                acc[mi][ni][r];
    }
    __syncthreads();
    if (g2 == 0) {
      #pragma unroll
      for (int mi = 0; mi < 2; ++mi) {
        #pragma unroll
        for (int ni = 0; ni < 2; ++ni) {
          #pragma unroll
          for (int r = 0; r < 4; ++r) {
            int ml = wm * 32 + mi * 16 + quad * 4 + r;
            int nl = wn * 32 + ni * 16 + l16;
            int m = m0 + ml;
            int n = n0 + nl;
            if (n < FCOUT) {
              float rv = fmaxf(acc[mi][ni][r] + sh.fs[ml][nl] + b_fc[n], 0.f);
              float msk = (t < length[m]) ? 1.f : 0.f;
              if (n < L_) {
                out[(size_t)m * (T_ * L_) + t * L_ + n] = rv * msk;
              } else if (n < L_ + H_) {
                out[(size_t)(B_ * T_ * L_) + (size_t)m * (T_ * H_) + t * H_ + (n - L_)] = rv * msk;
              } else if (n == L_ + H_) {
                out[(size_t)B_ * T_ * (L_ + H_) + m * T_ + t] = expf(rv) * msk;
              } else {
                out[(size_t)B_ * T_ * (L_ + H_ + 1) + m * T_ + t] = sigm(rv) * msk;
              }
            }
          }
        }
      }
    }
  }
}

// ---------------------------------------------------------------------------
extern "C" void kernel_launch(void* const* d_in, const int* in_sizes, int n_in,
                              void* d_out, int out_size, void* d_ws, size_t ws_size,
                              hipStream_t stream) {
  const float* image  = (const float*)d_in[0];
  const float* label  = (const float*)d_in[1];
  const int*   length = (const int*)  d_in[2];
  const float* W_h    = (const float*)d_in[3];
  const float* b_h    = (const float*)d_in[4];
  const float* W_m    = (const float*)d_in[5];
  const float* b_m    = (const float*)d_in[6];
  const float* W_ih   = (const float*)d_in[7];
  const float* W_hh   = (const float*)d_in[8];
  const float* b_ih   = (const float*)d_in[9];
  const float* b_hh   = (const float*)d_in[10];
  const float* W_fc   = (const float*)d_in[11];
  const float* b_fc   = (const float*)d_in[12];
  float* out = (float*)d_out;

  char* ws = (char*)d_ws;
  size_t off = 0;
  auto alloc = [&](size_t bytes) -> void* {
    void* p = ws + off;
    off = (off + bytes + 255) & ~(size_t)255;
    return p;
  };
  u16*   meanB = (u16*)  alloc((size_t)B_ * E_ * 2);
  u16*   WhB   = (u16*)  alloc((size_t)H_ * E_ * 2);
  u16*   WmB   = (u16*)  alloc((size_t)H_ * E_ * 2);
  u16*   WihE  = (u16*)  alloc((size_t)4 * H_ * E_ * 2);
  u16*   WihL  = (u16*)  alloc((size_t)4 * H_ * L_ * 2);
  u16*   WhhB  = (u16*)  alloc((size_t)4 * H_ * H_ * 2);
  u16*   WfcB  = (u16*)  alloc((size_t)FCPAD * H_ * 2);
  u16*   labB  = (u16*)  alloc((size_t)B_ * T_ * L_ * 2);
  float* gbase = (float*)alloc((size_t)B_ * 4 * H_ * 4);
  u16*   hbuf0 = (u16*)  alloc((size_t)B_ * H_ * 2);
  u16*   hbuf1 = (u16*)  alloc((size_t)B_ * H_ * 2);
  float* mS    = (float*)alloc((size_t)B_ * H_ * 4);

  auto cvt = [&](const float* in, u16* o, int rows, int src_rows, int in_ld,
                 int in_off, int cols) {
    long total4 = (long)rows * cols / 4;
    int blocks = (int)((total4 + 255) / 256);
    cvt_bf16_v4<<<blocks, 256, 0, stream>>>(in, o, src_rows, in_ld, in_off,
                                            cols / 4, total4);
  };

  // --- setup: weight/label conversion to bf16 ---
  cvt(W_h,  WhB,  H_,     H_,     E_,      0,  E_);
  cvt(W_m,  WmB,  H_,     H_,     E_,      0,  E_);
  cvt(W_ih, WihE, 4 * H_, 4 * H_, E_ + L_, 0,  E_);   // columns [0, E)
  cvt(W_ih, WihL, 4 * H_, 4 * H_, E_ + L_, E_, L_);   // columns [E, E+L)
  cvt(W_hh, WhhB, 4 * H_, 4 * H_, H_,      0,  H_);
  cvt(W_fc, WfcB, FCPAD,  FCOUT,  H_,      0,  H_);   // zero-padded rows
  cvt(label, labB, B_, B_, T_ * L_, 0, T_ * L_);

  img_mean_k<<<(B_ * E_ / 4) / 256, 256, 0, stream>>>(image, meanB);

  // --- setup GEMMs ---
  // h0 = tanh(mean @ W_h^T + b_h) -> bf16 (h_state[-1] in hbuf0)
  gemm_nt<1><<<dim3(B_ / 64, H_ / 64), 256, 0, stream>>>(
      meanB, E_, WhB, E_, E_, b_h, nullptr, nullptr, hbuf0, H_);
  // m0 = tanh(mean @ W_m^T + b_m) -> f32
  gemm_nt<2><<<dim3(B_ / 64, H_ / 64), 256, 0, stream>>>(
      meanB, E_, WmB, E_, E_, b_m, nullptr, mS, nullptr, H_);
  // gates_base = mean @ W_ihE^T + b_ih + b_hh -> f32
  gemm_nt<0><<<dim3(B_ / 64, (4 * H_) / 64), 256, 0, stream>>>(
      meanB, E_, WihE, E_, E_, b_ih, b_hh, gbase, nullptr, 4 * H_);

  // --- the scan: one launch per phase; kernel boundary = sync ---
  for (int p = 0; p <= T_; ++p) {
    u16* hcur  = (p & 1) ? hbuf1 : hbuf0;
    u16* hnext = (p & 1) ? hbuf0 : hbuf1;
    step_k<<<GJOBS + FJOBS, 512, 0, stream>>>(
        labB, WihL, WhhB, WfcB, gbase, b_fc, hcur, hnext, mS, length, out, p);
  }
}